// Round 5
// baseline (128.713 us; speedup 1.0000x reference)
//
#include <hip/hip_runtime.h>

// Kalman filter, reformulated:  out[b][p] = alpha_p + sum_t Z[p][t] x[b][t]
// 10 blocks x 512:
//   block 0   : 64x64 Riccati recursion (split-f16 MFMA, 2 raw barriers/step,
//               no vmcnt drains) WITH fused V-propagation kept in registers
//               (D-frag == B-frag layout identity), publishes W once at end
//   block 1   : prediction-phase row chains u_p, e_p; publishes U/E once
//   blocks 2-9: output GEMM; wait on 2 flags, then build Z and compute out
// ws (u64): WP[33*64] | UP[16*64] | EP[16] | FLAGS[2]  (tag in hi32)

constexpr int WP_OFF = 0;
constexpr int UP_OFF = 2112;
constexpr int EP_OFF = 3136;
constexpr int FL_OFF = 3152;
constexpr int WS_U64 = 3154;

typedef float    f32x4 __attribute__((ext_vector_type(4)));
typedef _Float16 f16x4 __attribute__((ext_vector_type(4)));
typedef _Float16 f16x8 __attribute__((ext_vector_type(8)));

#define MFMA16(a, b, c) __builtin_amdgcn_mfma_f32_16x16x16f16((a), (b), (c), 0, 0, 0)

template <int CTRL>
__device__ __forceinline__ float dpp_add(float x) {
  int v = __builtin_amdgcn_update_dpp(0, __builtin_bit_cast(int, x), CTRL, 0xf, 0xf, true);
  return x + __builtin_bit_cast(float, v);
}
__device__ __forceinline__ float sum16(float x) {
  x = dpp_add<0xB1>(x);   // quad_perm xor1
  x = dpp_add<0x4E>(x);   // quad_perm xor2
  x = dpp_add<0x141>(x);  // row_half_mirror (xor4)
  x = dpp_add<0x140>(x);  // row_mirror (xor8)
  return x;
}
__device__ __forceinline__ float sum64(float x) {
  x = sum16(x);
  x += __shfl_xor(x, 16, 64);
  x += __shfl_xor(x, 32, 64);
  return x;
}

__device__ __forceinline__ float spin_read(const unsigned long long* p, unsigned tag) {
  unsigned long long v = 0;
  for (int it = 0; it < (1 << 22); ++it) {
    v = __hip_atomic_load(p, __ATOMIC_RELAXED, __HIP_MEMORY_SCOPE_AGENT);
    if ((unsigned)(v >> 32) == tag) break;
  }
  union { unsigned u; float f; } cv; cv.u = (unsigned)v;
  return cv.f;
}
__device__ __forceinline__ void pub_write(unsigned long long* p, unsigned tag, float x) {
  union { float f; unsigned u; } cv; cv.f = x;
  __hip_atomic_store(p, ((unsigned long long)tag << 32) | cv.u,
                     __ATOMIC_RELAXED, __HIP_MEMORY_SCOPE_AGENT);
}
__device__ __forceinline__ void wait_flag(const unsigned long long* p, unsigned tag) {
  for (int it = 0; it < (1 << 20); ++it) {
    if ((unsigned)(__hip_atomic_load(p, __ATOMIC_RELAXED, __HIP_MEMORY_SCOPE_AGENT) >> 32) == tag)
      return;
    __builtin_amdgcn_s_sleep(16);
  }
}
// Barrier that waits only LDS ops — VMEM (prefetch) stays in flight.
__device__ __forceinline__ void lds_barrier() {
  asm volatile("s_waitcnt lgkmcnt(0)" ::: "memory");
  __builtin_amdgcn_sched_barrier(0);
  __builtin_amdgcn_s_barrier();
  __builtin_amdgcn_sched_barrier(0);
}

__global__ __launch_bounds__(512) void kalman_fused(
    const float* __restrict__ Fw, const float* __restrict__ Fb,
    const float* __restrict__ Hw, const float* __restrict__ Hb,
    const float* __restrict__ s0, const float* __restrict__ P0,
    const float* __restrict__ Qg, const float* __restrict__ Rg,
    const float* __restrict__ x, float* __restrict__ out,
    unsigned long long* __restrict__ ws) {
  __shared__ __align__(16) char smem[55040];
  const int tid  = threadIdx.x;
  const int lane = tid & 63;
  const int w    = tid >> 6;
  const int blk  = blockIdx.x;
  unsigned long long* wp = ws + WP_OFF;
  unsigned long long* up = ws + UP_OFF;
  unsigned long long* ep = ws + EP_OFF;

  if (blk == 0) {
    // ============ P/k Riccati recursion + in-register V-propagation ============
    _Float16* FF  = (_Float16*)smem;            // [16][65][8]  F frags (hi|lo)
    _Float16* TF  = (_Float16*)(smem + 16640);  // [16][64][8]  T frags (hi|lo)
    float*    PF  = (float*)(smem + 33024);     // [16][64][5]  Ppred C-frags
    float*    nred = (float*)(smem + 53504);    // [2][64]
    float*    mred = (float*)(smem + 54016);    // [4][64]

    const int l15 = lane & 15, g = lane >> 4;
    const int ti = w >> 1, half = w & 1;
    const int lp0 = 16 * (l15 >> 2) + 4 * g;
    const int rg  = l15 & 3;
    const int sr = tid >> 3, sc0 = (tid & 7) * 8;
    const int fi = (sr >> 4) * 4 + (sc0 >> 4);
    const int L0 = (sr & 15) + 16 * ((sc0 >> 2) & 3);
    const float R0 = Rg[0];
    const bool isV = (w < 2);    // V-strip waves: ct = w (cols 16w .. 16w+15)
    const int ct = w;

    auto FFp = [&](int f, int l) { return FF + (f * 65 + l) * 8; };
    auto TFp = [&](int f, int l) { return TF + (f * 64 + l) * 8; };
    auto PFi = [&](int f, int l, int r) { return (f * 64 + l) * 5 + r; };

    auto stageF = [&](f32x4 a, f32x4 b) {
      f16x8 pa, pb;
      #pragma unroll
      for (int u = 0; u < 4; ++u) {
        const _Float16 ha = (_Float16)a[u];
        pa[u] = ha; pa[4 + u] = (_Float16)((a[u] - (float)ha) * 2048.0f);
        const _Float16 hb = (_Float16)b[u];
        pb[u] = hb; pb[4 + u] = (_Float16)((b[u] - (float)hb) * 2048.0f);
      }
      *(f16x8*)FFp(fi, L0)      = pa;
      *(f16x8*)FFp(fi, L0 + 16) = pb;
    };

    // ---- prologue ----
    float qf0[4], qf1[4];
    #pragma unroll
    for (int reg = 0; reg < 4; ++reg) {
      qf0[reg] = Qg[(16 * ti + 4 * g + reg) * 64 + 16 * (2 * half) + l15];
      qf1[reg] = Qg[(16 * ti + 4 * g + reg) * 64 + 16 * (2 * half + 1) + l15];
    }
    #pragma unroll
    for (int u = 0; u < 8; ++u) {
      const int cc = sc0 + u;
      PF[PFi((sr >> 4) * 4 + (cc >> 4), 16 * ((sr & 15) >> 2) + (cc & 15), sr & 3)] =
          P0[sr * 64 + cc];
    }
    f32x4 fpa = *(const f32x4*)(Fw + sr * 64 + sc0);
    f32x4 fpb = *(const f32x4*)(Fw + sr * 64 + sc0 + 4);
    stageF(fpa, fpb);
    float hcur = Hw[lane], hprev = 0.f, hnext = 0.f;
    float fbcur = Fb[lane], fbnext = 0.f;
    float hbcur = Hb[0], hbnext = 0.f;

    // V^(0): col0 = s0, rest 0 — stored as split-f16 B-frags (k-tile = kc)
    const float s0v = s0[lane];
    f16x4 VbH[4], VbL[4];
    #pragma unroll
    for (int kc = 0; kc < 4; ++kc)
      #pragma unroll
      for (int j = 0; j < 4; ++j) {
        const float sv = __shfl(s0v, 16 * kc + 4 * g + j, 64);
        const float v = (ct == 0 && l15 == 0) ? sv : 0.f;
        const _Float16 h_ = (_Float16)v;
        VbH[kc][j] = h_;
        VbL[kc][j] = (_Float16)((v - (float)h_) * 2048.0f);
      }
    f32x4 vpv[4];
    float qreg = 0.f;
    __syncthreads();

    for (int t = 0; t < 32; ++t) {
      // ---- phase 1: kfin + V-epilogue + V-matmul + A-cvt + mm1 ----
      if (t + 1 < 32) {
        fpa = *(const f32x4*)(Fw + (size_t)(t + 1) * 4096 + sr * 64 + sc0);
        fpb = *(const f32x4*)(Fw + (size_t)(t + 1) * 4096 + sr * 64 + sc0 + 4);
        hnext  = Hw[(t + 1) * 64 + lane];
        fbnext = Fb[(t + 1) * 64 + lane];
        hbnext = Hb[t + 1];
      }
      float kv = 0.f, mr = 0.f;
      if (t > 0) {
        const float n = nred[lane] + nred[64 + lane];
        mr = mred[lane] + mred[64 + lane] + mred[128 + lane] + mred[192 + lane];
        const float s = sum64(hprev * n);
        kv = n / (s + R0);
      }
      if (isV) {
        if (t > 0) {  // apply k_{t-1}: Vnew = Vp - k q^T; col t := k
          #pragma unroll
          for (int rt = 0; rt < 4; ++rt)
            #pragma unroll
            for (int j = 0; j < 4; ++j) {
              const float kr2 = __shfl(kv, 16 * rt + 4 * g + j, 64);
              float val = vpv[rt][j] - kr2 * qreg;
              if (l15 == t - 16 * ct) val = kr2;
              const _Float16 h_ = (_Float16)val;
              VbH[rt][j] = h_;
              VbL[rt][j] = (_Float16)((val - (float)h_) * 2048.0f);
            }
        }
        // Vp = F_t * V (+ Fb_t in col 0); D-frags land directly as next B-frags
        #pragma unroll
        for (int rt = 0; rt < 4; ++rt) {
          f32x4 am, a1;
          #pragma unroll
          for (int r = 0; r < 4; ++r) {
            const float bsh = __shfl(fbcur, 16 * rt + 4 * g + r, 64);
            am[r] = (ct == 0 && l15 == 0) ? bsh : 0.f;
            a1[r] = 0.f;
          }
          #pragma unroll
          for (int kc = 0; kc < 4; ++kc) {
            const f16x8 av = *(const f16x8*)FFp(rt * 4 + kc, lane);
            const f16x4 ah = __builtin_shufflevector(av, av, 0, 1, 2, 3);
            const f16x4 al = __builtin_shufflevector(av, av, 4, 5, 6, 7);
            am = MFMA16(ah, VbH[kc], am);
            a1 = MFMA16(ah, VbL[kc], a1);
            a1 = MFMA16(al, VbH[kc], a1);
          }
          vpv[rt] = am + a1 * (1.0f / 2048.0f);
        }
      }
      // A-cvt for P (rank-1 fused)
      const float kr = __shfl(kv, l15 + 16 * ti, 64);
      f16x4 Ah[4], Al[4];
      #pragma unroll
      for (int kc = 0; kc < 4; ++kc) {
        #pragma unroll
        for (int j = 0; j < 4; ++j) {
          const float mcol = __shfl(mr, 16 * kc + 4 * g + j, 64);
          const float pv = PF[PFi(ti * 4 + kc, lp0 + j, rg)] - kr * mcol;
          const _Float16 h_ = (_Float16)pv;
          Ah[kc][j] = h_;
          Al[kc][j] = (_Float16)((pv - (float)h_) * 2048.0f);
        }
      }
      f16x4 FAh[4], FAl[4];  // pre-read mm2 A-operand (F_t) before barrier A
      #pragma unroll
      for (int kc = 0; kc < 4; ++kc) {
        const f16x8 av = *(const f16x8*)FFp(ti * 4 + kc, lane);
        FAh[kc] = __builtin_shufflevector(av, av, 0, 1, 2, 3);
        FAl[kc] = __builtin_shufflevector(av, av, 4, 5, 6, 7);
      }
      #pragma unroll
      for (int s2 = 0; s2 < 2; ++s2) {  // mm1: T = P_work * F_t^T
        const int tj = 2 * half + s2;
        f32x4 am = {0.f, 0.f, 0.f, 0.f}, a1 = {0.f, 0.f, 0.f, 0.f}, a2 = {0.f, 0.f, 0.f, 0.f};
        #pragma unroll
        for (int kc = 0; kc < 4; ++kc) {
          const f16x8 bv = *(const f16x8*)FFp(tj * 4 + kc, lane);
          const f16x4 bh = __builtin_shufflevector(bv, bv, 0, 1, 2, 3);
          const f16x4 bl = __builtin_shufflevector(bv, bv, 4, 5, 6, 7);
          am = MFMA16(Ah[kc], bh, am);
          a1 = MFMA16(Ah[kc], bl, a1);
          a2 = MFMA16(Al[kc], bh, a2);
        }
        const f32x4 outv = am + (a1 + a2) * (1.0f / 2048.0f);
        f16x8 tv;
        #pragma unroll
        for (int j = 0; j < 4; ++j) {
          const _Float16 h_ = (_Float16)outv[j];
          tv[j] = h_;
          tv[4 + j] = (_Float16)((outv[j] - (float)h_) * 2048.0f);
        }
        *(f16x8*)TFp(ti * 4 + tj, lane) = tv;
      }
      lds_barrier();  // A

      // ---- phase 2: stage F_{t+1} + mm2 + reductions + q ----
      if (t + 1 < 32) stageF(fpa, fpb);
      f32x4 pout[2];
      #pragma unroll
      for (int s2 = 0; s2 < 2; ++s2) {
        const int tj = 2 * half + s2;
        f32x4 am = {0.f, 0.f, 0.f, 0.f}, a1 = {0.f, 0.f, 0.f, 0.f}, a2 = {0.f, 0.f, 0.f, 0.f};
        #pragma unroll
        for (int kc = 0; kc < 4; ++kc) {
          const f16x8 bv = *(const f16x8*)TFp(kc * 4 + tj, lane);
          const f16x4 bh = __builtin_shufflevector(bv, bv, 0, 1, 2, 3);
          const f16x4 bl = __builtin_shufflevector(bv, bv, 4, 5, 6, 7);
          am = MFMA16(FAh[kc], bh, am);
          a1 = MFMA16(FAh[kc], bl, a1);
          a2 = MFMA16(FAl[kc], bh, a2);
        }
        pout[s2] = am + (a1 + a2) * (1.0f / 2048.0f);
        #pragma unroll
        for (int reg = 0; reg < 4; ++reg) {
          pout[s2][reg] += (s2 ? qf1[reg] : qf0[reg]);
          PF[PFi(ti * 4 + tj, lane, reg)] = pout[s2][reg];
        }
      }
      const float hcA = __shfl(hcur, 16 * (2 * half) + l15, 64);
      const float hcB = __shfl(hcur, 16 * (2 * half + 1) + l15, 64);
      float hr[4];
      #pragma unroll
      for (int reg = 0; reg < 4; ++reg) hr[reg] = __shfl(hcur, 16 * ti + 4 * g + reg, 64);
      #pragma unroll
      for (int reg = 0; reg < 4; ++reg) {
        float np = pout[0][reg] * hcA + pout[1][reg] * hcB;
        np = sum16(np);
        if (l15 == 0) nred[half * 64 + 16 * ti + 4 * g + reg] = np;
      }
      float mp0 = 0.f, mp1 = 0.f;
      #pragma unroll
      for (int reg = 0; reg < 4; ++reg) {
        mp0 += pout[0][reg] * hr[reg];
        mp1 += pout[1][reg] * hr[reg];
      }
      mp0 += __shfl_xor(mp0, 16, 64); mp0 += __shfl_xor(mp0, 32, 64);
      mp1 += __shfl_xor(mp1, 16, 64); mp1 += __shfl_xor(mp1, 32, 64);
      if (g == 0) {
        mred[ti * 64 + 16 * (2 * half) + l15]     = mp0;
        mred[ti * 64 + 16 * (2 * half + 1) + l15] = mp1;
      }
      if (isV) {  // q = h_t^T Vp (+ Hb_t at col 0)
        float qp = 0.f;
        #pragma unroll
        for (int rt = 0; rt < 4; ++rt)
          #pragma unroll
          for (int r = 0; r < 4; ++r)
            qp += __shfl(hcur, 16 * rt + 4 * g + r, 64) * vpv[rt][r];
        qp += __shfl_xor(qp, 16, 64);
        qp += __shfl_xor(qp, 32, 64);
        if (ct == 0 && l15 == 0) qp += hbcur;
        qreg = qp;
      }
      lds_barrier();  // B
      hprev = hcur; hcur = hnext; fbcur = fbnext; hbcur = hbnext;
    }

    // ---- finalize k_31, final V epilogue, publish W ----
    {
      const float n = nred[lane] + nred[64 + lane];
      const float s = sum64(hprev * n);
      const float k31 = n / (s + R0);
      if (isV) {
        #pragma unroll
        for (int rt = 0; rt < 4; ++rt)
          #pragma unroll
          for (int j = 0; j < 4; ++j) {
            const float kr2 = __shfl(k31, 16 * rt + 4 * g + j, 64);
            const float val = vpv[rt][j] - kr2 * qreg;
            pub_write(&wp[(16 * ct + l15) * 64 + 16 * rt + 4 * g + j], 1u, val);
          }
      }
      if (w == 2) pub_write(&wp[32 * 64 + lane], 1u, k31);
    }
    __syncthreads();
    if (tid == 0) pub_write(&ws[FL_OFF], 1u, 0.f);
    return;
  }

  if (blk == 1) {
    // ================= prediction-phase chains u_p, e_p =================
    for (int pi = 0; pi < 2; ++pi) {
      const int p = pi ? (15 - w) : w;
      const int q = 32 + p;
      float r = Hw[q * 64 + lane];
      float eacc = 0.f;
      for (int s = 0; s <= p; ++s) {
        const int m = q - s;
        eacc += r * Fb[m * 64 + lane];
        const float* Fm = Fw + (size_t)m * 4096;
        float r0 = 0.f, r1 = 0.f, r2 = 0.f, r3 = 0.f;
        for (int j = 0; j < 64; j += 4) {
          r0 += __shfl(r, j,     64) * Fm[j * 64 + lane];
          r1 += __shfl(r, j + 1, 64) * Fm[(j + 1) * 64 + lane];
          r2 += __shfl(r, j + 2, 64) * Fm[(j + 2) * 64 + lane];
          r3 += __shfl(r, j + 3, 64) * Fm[(j + 3) * 64 + lane];
        }
        r = (r0 + r1) + (r2 + r3);
      }
      eacc = sum64(eacc);
      pub_write(&up[p * 64 + lane], 1u, r);
      if (lane == 0) pub_write(&ep[p], 1u, eacc + Hb[q]);
    }
    __syncthreads();
    if (tid == 0) pub_write(&ws[FL_OFF + 1], 1u, 0.f);
    return;
  }

  // ================= output GEMM blocks (blk 2..9) =================
  {
    float* Ul = (float*)smem;             // [16][68]
    float* Wl = (float*)(smem + 4352);    // [33][68]
    float* Zl = (float*)(smem + 13328);   // [16][34]
    float* El = (float*)(smem + 15504);   // [16]
    const int b = (blk - 2) * 512 + tid;
    f32x4 xr[8];
    const f32x4* xp = (const f32x4*)(x + (size_t)b * 32);
    #pragma unroll
    for (int u = 0; u < 8; ++u) xr[u] = xp[u];

    if (tid == 0) {
      wait_flag(&ws[FL_OFF], 1u);
      wait_flag(&ws[FL_OFF + 1], 1u);
    }
    __syncthreads();
    for (int idx = tid; idx < 1024; idx += 512)
      Ul[(idx >> 6) * 68 + (idx & 63)] = spin_read(&up[idx], 1u);
    for (int idx = tid; idx < 2112; idx += 512)
      Wl[(idx >> 6) * 68 + (idx & 63)] = spin_read(&wp[idx], 1u);
    if (tid < 16) El[tid] = spin_read(&ep[tid], 1u);
    __syncthreads();
    for (int idx = tid; idx < 528; idx += 512) {
      const int p = idx / 33, cc = idx - p * 33;
      const float* Up = Ul + p * 68;
      const float* Wc = Wl + cc * 68;
      float a0 = 0.f, a1 = 0.f, a2 = 0.f, a3 = 0.f;
      #pragma unroll 4
      for (int i = 0; i < 64; i += 4) {
        a0 += Up[i] * Wc[i];         a1 += Up[i + 1] * Wc[i + 1];
        a2 += Up[i + 2] * Wc[i + 2]; a3 += Up[i + 3] * Wc[i + 3];
      }
      float z = (a0 + a1) + (a2 + a3);
      if (cc == 0) z += El[p];
      Zl[p * 34 + cc] = z;
    }
    __syncthreads();
    float acc[16];
    #pragma unroll
    for (int p = 0; p < 16; ++p) acc[p] = Zl[p * 34];
    #pragma unroll
    for (int u = 0; u < 8; ++u) {
      #pragma unroll
      for (int e = 0; e < 4; ++e) {
        const float xval = xr[u][e];
        const int t = u * 4 + e;
        #pragma unroll
        for (int p = 0; p < 16; ++p) acc[p] += Zl[p * 34 + 1 + t] * xval;
      }
    }
    float4* op = (float4*)(out + (size_t)b * 16);
    op[0] = make_float4(acc[0], acc[1], acc[2], acc[3]);
    op[1] = make_float4(acc[4], acc[5], acc[6], acc[7]);
    op[2] = make_float4(acc[8], acc[9], acc[10], acc[11]);
    op[3] = make_float4(acc[12], acc[13], acc[14], acc[15]);
  }
}

extern "C" void kernel_launch(void* const* d_in, const int* in_sizes, int n_in,
                              void* d_out, int out_size, void* d_ws, size_t ws_size,
                              hipStream_t stream) {
  (void)in_sizes; (void)n_in; (void)out_size; (void)ws_size;
  const float* x  = (const float*)d_in[0];
  const float* Fw = (const float*)d_in[1];
  const float* Fb = (const float*)d_in[2];
  const float* Hw = (const float*)d_in[3];
  const float* Hb = (const float*)d_in[4];
  const float* s0 = (const float*)d_in[5];
  const float* P0 = (const float*)d_in[6];
  const float* Q  = (const float*)d_in[7];
  const float* R  = (const float*)d_in[8];
  float* out = (float*)d_out;
  unsigned long long* ws = (unsigned long long*)d_ws;

  hipMemsetAsync(d_ws, 0, WS_U64 * sizeof(unsigned long long), stream);
  kalman_fused<<<10, 512, 0, stream>>>(Fw, Fb, Hw, Hb, s0, P0, Q, R, x, out, ws);
}